// Round 1
// baseline (656.509 us; speedup 1.0000x reference)
//
#include <hip/hip_runtime.h>
#include <hip/hip_bf16.h>
#include <cstdint>
#include <cstddef>

#define TT 64
#define CC 32
#define FF 16
#define HWSZ 1024
#define NPIX 16384   // B*H*W = 16*32*32

__device__ __forceinline__ float bf2f(unsigned int u16) {
  union { unsigned int u; float f; } c;
  c.u = u16 << 16;
  return c.f;
}
__device__ __forceinline__ unsigned int f2bf(float f) {
  union { float f; unsigned int u; } c;
  c.f = f;
  unsigned int u = c.u;
  return (u + 0x7fffu + ((u >> 16) & 1u)) >> 16;  // RNE
}
__device__ __forceinline__ float hsig(float x) {
  return fminf(fmaxf(fmaf(x, 0.2f, 0.5f), 0.0f), 1.0f);
}
__device__ __forceinline__ float tanhf_fast(float x) {
  float e = __expf(2.0f * x);
  return 1.0f - 2.0f / (e + 1.0f);
}

// Block: 256 threads = 4 waves. lane = pixel-in-block (64 px/block).
// Wave G computes gate slice [16G, 16G+16) for its 64 pixels; weights are
// wave-uniform -> scalar loads -> v_fmac with SGPR operand.
__global__ __launch_bounds__(256) void lstm_kernel(
    const float* __restrict__ x,
    const float* __restrict__ Wf, const float* __restrict__ Uf, const float* __restrict__ bfp,
    const float* __restrict__ Wb, const float* __restrict__ Ub, const float* __restrict__ bbp,
    unsigned short* __restrict__ hf_out, unsigned short* __restrict__ hb_out)
{
  const int dir = blockIdx.y;
  const float* __restrict__ Wp = dir ? Wb : Wf;
  const float* __restrict__ Up = dir ? Ub : Uf;
  const float* __restrict__ bp = dir ? bbp : bfp;
  unsigned short* __restrict__ hout = dir ? hb_out : hf_out;

  const int tid  = threadIdx.x;
  const int lane = tid & 63;
  const int G    = __builtin_amdgcn_readfirstlane(tid >> 6);  // gate group, wave-uniform

  const int p  = blockIdx.x * 64 + lane;  // global pixel id (b,hw)
  const int b  = p >> 10;
  const int hw = p & 1023;

  __shared__ float Zb[64 * 64];   // [gate][px]
  __shared__ float Hb[16 * 64];   // [f][px]

  for (int i = tid; i < 16 * 64; i += 256) Hb[i] = 0.0f;

  float cst[4] = {0.f, 0.f, 0.f, 0.f};

  float binit[16];
  #pragma unroll
  for (int j = 0; j < 16; ++j) binit[j] = bp[16 * G + j];

  const float* __restrict__ Wg = Wp + 16 * G;  // W[k][16G + j], stride 64
  const float* __restrict__ Ug = Up + 16 * G;

  __syncthreads();

  for (int s = 0; s < TT; ++s) {
    const int t = dir ? (TT - 1 - s) : s;
    const float* xp = x + ((size_t)(b * TT + t) * HWSZ + hw) * CC;

    float4 xv[8];
    #pragma unroll
    for (int i = 0; i < 8; ++i) xv[i] = reinterpret_cast<const float4*>(xp)[i];
    const float* xs = reinterpret_cast<const float*>(xv);

    float z[16];
    #pragma unroll
    for (int j = 0; j < 16; ++j) z[j] = binit[j];

    // z += x @ W   (x: per-lane VGPR, W: wave-uniform scalar)
    #pragma unroll
    for (int k = 0; k < CC; ++k) {
      const float xk = xs[k];
      #pragma unroll
      for (int j = 0; j < 16; ++j) z[j] = fmaf(xk, Wg[k * 64 + j], z[j]);
    }
    // z += h @ U   (h from LDS, conflict-free: consecutive lanes, consecutive addrs)
    #pragma unroll
    for (int k = 0; k < FF; ++k) {
      const float hk = Hb[k * 64 + lane];
      #pragma unroll
      for (int j = 0; j < 16; ++j) z[j] = fmaf(hk, Ug[k * 64 + j], z[j]);
    }

    #pragma unroll
    for (int j = 0; j < 16; ++j) Zb[(16 * G + j) * 64 + lane] = z[j];
    __syncthreads();

    // update: this thread owns pixel=lane, f in [4G, 4G+4)
    float hv[4];
    #pragma unroll
    for (int m = 0; m < 4; ++m) {
      const int f = 4 * G + m;
      const float zi = Zb[(f     ) * 64 + lane];
      const float zf = Zb[(16 + f) * 64 + lane];
      const float zg = Zb[(32 + f) * 64 + lane];
      const float zo = Zb[(48 + f) * 64 + lane];
      const float ig = hsig(zi);
      const float fg = hsig(zf);
      const float og = hsig(zo);
      const float gg = tanhf_fast(zg);
      cst[m] = fmaf(fg, cst[m], ig * gg);
      hv[m]  = og * tanhf_fast(cst[m]);
    }
    #pragma unroll
    for (int m = 0; m < 4; ++m) Hb[(4 * G + m) * 64 + lane] = hv[m];

    // store h (bf16) to global: [pos][16], this thread writes f=4G..4G+3 (8B store)
    const size_t pos = (size_t)(b * TT + t) * HWSZ + hw;
    uint2 pk;
    pk.x = f2bf(hv[0]) | (f2bf(hv[1]) << 16);
    pk.y = f2bf(hv[2]) | (f2bf(hv[3]) << 16);
    *reinterpret_cast<uint2*>(hout + pos * 16 + 4 * G) = pk;

    __syncthreads();
  }
}

// One thread per (b,t,h,w) position: 32 bf16 in -> 16 -> 16 -> 10 fp32 out.
__global__ __launch_bounds__(256) void dense_kernel(
    const unsigned short* __restrict__ hf, const unsigned short* __restrict__ hb,
    const float* __restrict__ w1, const float* __restrict__ b1,
    const float* __restrict__ w2, const float* __restrict__ b2,
    const float* __restrict__ w3, const float* __restrict__ b3,
    float* __restrict__ out)
{
  const size_t pos = (size_t)blockIdx.x * 256 + threadIdx.x;

  const uint4* hf4 = reinterpret_cast<const uint4*>(hf) + pos * 2;
  const uint4* hb4 = reinterpret_cast<const uint4*>(hb) + pos * 2;
  uint4 q0 = hf4[0], q1 = hf4[1], q2 = hb4[0], q3 = hb4[1];
  unsigned int uw[16] = {q0.x, q0.y, q0.z, q0.w, q1.x, q1.y, q1.z, q1.w,
                         q2.x, q2.y, q2.z, q2.w, q3.x, q3.y, q3.z, q3.w};
  float hin[32];
  #pragma unroll
  for (int i = 0; i < 16; ++i) {
    hin[2 * i]     = bf2f(uw[i] & 0xffffu);
    hin[2 * i + 1] = bf2f(uw[i] >> 16);
  }

  float a1[16];
  #pragma unroll
  for (int j = 0; j < 16; ++j) a1[j] = b1[j];
  #pragma unroll
  for (int k = 0; k < 32; ++k) {
    const float v = hin[k];
    #pragma unroll
    for (int j = 0; j < 16; ++j) a1[j] = fmaf(v, w1[k * 16 + j], a1[j]);
  }

  float a2[16];
  #pragma unroll
  for (int j = 0; j < 16; ++j) a2[j] = b2[j];
  #pragma unroll
  for (int k = 0; k < 16; ++k) {
    const float v = a1[k];
    #pragma unroll
    for (int j = 0; j < 16; ++j) a2[j] = fmaf(v, w2[k * 16 + j], a2[j]);
  }

  float a3[10];
  #pragma unroll
  for (int j = 0; j < 10; ++j) a3[j] = b3[j];
  #pragma unroll
  for (int k = 0; k < 16; ++k) {
    const float v = a2[k];
    #pragma unroll
    for (int j = 0; j < 10; ++j) a3[j] = fmaf(v, w3[k * 10 + j], a3[j]);
  }

  float2* o2 = reinterpret_cast<float2*>(out + pos * 10);
  o2[0] = make_float2(a3[0], a3[1]);
  o2[1] = make_float2(a3[2], a3[3]);
  o2[2] = make_float2(a3[4], a3[5]);
  o2[3] = make_float2(a3[6], a3[7]);
  o2[4] = make_float2(a3[8], a3[9]);
}

extern "C" void kernel_launch(void* const* d_in, const int* in_sizes, int n_in,
                              void* d_out, int out_size, void* d_ws, size_t ws_size,
                              hipStream_t stream) {
  const float* x   = (const float*)d_in[0];
  const float* Wf  = (const float*)d_in[1];
  const float* Uf  = (const float*)d_in[2];
  const float* bfp = (const float*)d_in[3];
  const float* Wb  = (const float*)d_in[4];
  const float* Ub  = (const float*)d_in[5];
  const float* bbp = (const float*)d_in[6];
  const float* w1  = (const float*)d_in[7];
  const float* b1  = (const float*)d_in[8];
  const float* w2  = (const float*)d_in[9];
  const float* b2  = (const float*)d_in[10];
  const float* w3  = (const float*)d_in[11];
  const float* b3  = (const float*)d_in[12];

  unsigned short* hfbuf = (unsigned short*)d_ws;                 // 16M bf16 = 33.5 MB
  unsigned short* hbbuf = hfbuf + (size_t)NPIX * TT * FF;        // +33.5 MB

  lstm_kernel<<<dim3(256, 2), 256, 0, stream>>>(x, Wf, Uf, bfp, Wb, Ub, bbp, hfbuf, hbbuf);

  const int npos = NPIX * TT;  // 1,048,576
  dense_kernel<<<npos / 256, 256, 0, stream>>>(hfbuf, hbbuf, w1, b1, w2, b2, w3, b3,
                                               (float*)d_out);
}

// Round 2
// 620.239 us; speedup vs baseline: 1.0585x; 1.0585x over previous
//
#include <hip/hip_runtime.h>
#include <hip/hip_bf16.h>
#include <cstdint>
#include <cstddef>

#define TT 64
#define CC 32
#define FF 16
#define HWSZ 1024
#define NPIX 16384   // B*H*W = 16*32*32

__device__ __forceinline__ float bf2f(unsigned int u16) {
  union { unsigned int u; float f; } c;
  c.u = u16 << 16;
  return c.f;
}
__device__ __forceinline__ unsigned int f2bf(float f) {
  union { float f; unsigned int u; } c;
  c.f = f;
  unsigned int u = c.u;
  return (u + 0x7fffu + ((u >> 16) & 1u)) >> 16;  // RNE
}
__device__ __forceinline__ float hsig(float x) {
  return fminf(fmaxf(fmaf(x, 0.2f, 0.5f), 0.0f), 1.0f);
}
__device__ __forceinline__ float tanhf_fast(float x) {
  float e = __expf(2.0f * x);
  return 1.0f - 2.0f / (e + 1.0f);
}

// ---------------------------------------------------------------------------
// Fold the 3 linear layers: Wc = w1@w2@w3 [32x10], bc = b1@w2@w3 + b2@w3 + b3.
// One block, 512 threads, runs in a few microseconds.
// ---------------------------------------------------------------------------
__global__ __launch_bounds__(512) void fold_kernel(
    const float* __restrict__ w1, const float* __restrict__ b1,
    const float* __restrict__ w2, const float* __restrict__ b2,
    const float* __restrict__ w3, const float* __restrict__ b3,
    float* __restrict__ Wc, float* __restrict__ bc)
{
  __shared__ float w23[16 * 10];
  __shared__ float bb2[16];
  const int t = threadIdx.x;

  if (t < 160) {
    const int k = t / 10, j = t % 10;
    float s = 0.0f;
    #pragma unroll
    for (int m = 0; m < 16; ++m) s = fmaf(w2[k * 16 + m], w3[m * 10 + j], s);
    w23[t] = s;
  }
  if (t < 16) {
    float s = b2[t];
    #pragma unroll
    for (int m = 0; m < 16; ++m) s = fmaf(b1[m], w2[m * 16 + t], s);
    bb2[t] = s;
  }
  __syncthreads();
  if (t < 320) {
    const int k = t / 10, j = t % 10;
    float s = 0.0f;
    #pragma unroll
    for (int m = 0; m < 16; ++m) s = fmaf(w1[k * 16 + m], w23[m * 10 + j], s);
    Wc[t] = s;
  }
  if (t < 10) {
    float s = b3[t];
    #pragma unroll
    for (int m = 0; m < 16; ++m) s = fmaf(bb2[m], w3[m * 10 + t], s);
    bc[t] = s;
  }
}

// ---------------------------------------------------------------------------
// LSTM: block = 512 threads = 8 waves, 64 pixels (lane = pixel).
// Wave w computes gate slice [8w, 8w+8) for all 64 pixels; weights are
// wave-uniform -> s_load + v_fmac with SGPR operand.
// 512 blocks x 8 waves = 4096 waves = 4 waves/SIMD (was 2).
// ---------------------------------------------------------------------------
__global__ __launch_bounds__(512) void lstm_kernel(
    const float* __restrict__ x,
    const float* __restrict__ Wf, const float* __restrict__ Uf, const float* __restrict__ bfp,
    const float* __restrict__ Wb, const float* __restrict__ Ub, const float* __restrict__ bbp,
    unsigned short* __restrict__ hf_out, unsigned short* __restrict__ hb_out)
{
  const int dir = blockIdx.y;
  const float* __restrict__ Wp = dir ? Wb : Wf;
  const float* __restrict__ Up = dir ? Ub : Uf;
  const float* __restrict__ bp = dir ? bbp : bfp;
  unsigned short* __restrict__ hout = dir ? hb_out : hf_out;

  const int tid  = threadIdx.x;
  const int lane = tid & 63;
  const int w    = __builtin_amdgcn_readfirstlane(tid >> 6);  // wave id 0..7

  const int p  = blockIdx.x * 64 + lane;  // global pixel id (b,hw)
  const int b  = p >> 10;
  const int hw = p & 1023;

  __shared__ float Zb[64 * 64];   // [gate][px]
  __shared__ float Hb[16 * 64];   // [f][px]

  for (int i = tid; i < 16 * 64; i += 512) Hb[i] = 0.0f;

  float cst[2] = {0.f, 0.f};

  float binit[8];
  #pragma unroll
  for (int j = 0; j < 8; ++j) binit[j] = bp[8 * w + j];

  const float* __restrict__ Wg = Wp + 8 * w;  // W[k][8w + j], stride 64
  const float* __restrict__ Ug = Up + 8 * w;

  __syncthreads();

  for (int s = 0; s < TT; ++s) {
    const int t = dir ? (TT - 1 - s) : s;
    const float* xp = x + ((size_t)(b * TT + t) * HWSZ + hw) * CC;

    float4 xv[8];
    #pragma unroll
    for (int i = 0; i < 8; ++i) xv[i] = reinterpret_cast<const float4*>(xp)[i];
    const float* xs = reinterpret_cast<const float*>(xv);

    float z[8];
    #pragma unroll
    for (int j = 0; j < 8; ++j) z[j] = binit[j];

    // z += x @ W   (x: per-lane VGPR, W: wave-uniform scalar)
    #pragma unroll
    for (int k = 0; k < CC; ++k) {
      const float xk = xs[k];
      #pragma unroll
      for (int j = 0; j < 8; ++j) z[j] = fmaf(xk, Wg[k * 64 + j], z[j]);
    }
    // z += h @ U   (h from LDS, conflict-free: consecutive lanes, consecutive addrs)
    #pragma unroll
    for (int k = 0; k < FF; ++k) {
      const float hk = Hb[k * 64 + lane];
      #pragma unroll
      for (int j = 0; j < 8; ++j) z[j] = fmaf(hk, Ug[k * 64 + j], z[j]);
    }

    #pragma unroll
    for (int j = 0; j < 8; ++j) Zb[(8 * w + j) * 64 + lane] = z[j];
    __syncthreads();

    // update: this thread owns pixel=lane, f in {2w, 2w+1}
    float hv[2];
    #pragma unroll
    for (int m = 0; m < 2; ++m) {
      const int f = 2 * w + m;
      const float zi = Zb[(f     ) * 64 + lane];
      const float zf = Zb[(16 + f) * 64 + lane];
      const float zg = Zb[(32 + f) * 64 + lane];
      const float zo = Zb[(48 + f) * 64 + lane];
      const float ig = hsig(zi);
      const float fg = hsig(zf);
      const float og = hsig(zo);
      const float gg = tanhf_fast(zg);
      cst[m] = fmaf(fg, cst[m], ig * gg);
      hv[m]  = og * tanhf_fast(cst[m]);
    }
    #pragma unroll
    for (int m = 0; m < 2; ++m) Hb[(2 * w + m) * 64 + lane] = hv[m];

    // store h (bf16) to global: [pos][16], this thread writes f = 2w, 2w+1 (4B)
    const size_t pos = (size_t)(b * TT + t) * HWSZ + hw;
    const unsigned int pk = f2bf(hv[0]) | (f2bf(hv[1]) << 16);
    *reinterpret_cast<unsigned int*>(hout + pos * 16 + 2 * w) = pk;

    __syncthreads();
  }
}

// ---------------------------------------------------------------------------
// Dense (collapsed): one thread per position, 32 bf16 in -> 10 fp32 out.
// ---------------------------------------------------------------------------
__global__ __launch_bounds__(256) void dense_kernel(
    const unsigned short* __restrict__ hf, const unsigned short* __restrict__ hb,
    const float* __restrict__ Wc, const float* __restrict__ bc,
    float* __restrict__ out)
{
  const size_t pos = (size_t)blockIdx.x * 256 + threadIdx.x;

  const uint4* hf4 = reinterpret_cast<const uint4*>(hf) + pos * 2;
  const uint4* hb4 = reinterpret_cast<const uint4*>(hb) + pos * 2;
  uint4 q0 = hf4[0], q1 = hf4[1], q2 = hb4[0], q3 = hb4[1];
  unsigned int uw[16] = {q0.x, q0.y, q0.z, q0.w, q1.x, q1.y, q1.z, q1.w,
                         q2.x, q2.y, q2.z, q2.w, q3.x, q3.y, q3.z, q3.w};
  float hin[32];
  #pragma unroll
  for (int i = 0; i < 16; ++i) {
    hin[2 * i]     = bf2f(uw[i] & 0xffffu);
    hin[2 * i + 1] = bf2f(uw[i] >> 16);
  }

  float acc[10];
  #pragma unroll
  for (int j = 0; j < 10; ++j) acc[j] = bc[j];
  #pragma unroll
  for (int k = 0; k < 32; ++k) {
    const float v = hin[k];
    #pragma unroll
    for (int j = 0; j < 10; ++j) acc[j] = fmaf(v, Wc[k * 10 + j], acc[j]);
  }

  float2* o2 = reinterpret_cast<float2*>(out + pos * 10);
  o2[0] = make_float2(acc[0], acc[1]);
  o2[1] = make_float2(acc[2], acc[3]);
  o2[2] = make_float2(acc[4], acc[5]);
  o2[3] = make_float2(acc[6], acc[7]);
  o2[4] = make_float2(acc[8], acc[9]);
}

extern "C" void kernel_launch(void* const* d_in, const int* in_sizes, int n_in,
                              void* d_out, int out_size, void* d_ws, size_t ws_size,
                              hipStream_t stream) {
  const float* x   = (const float*)d_in[0];
  const float* Wf  = (const float*)d_in[1];
  const float* Uf  = (const float*)d_in[2];
  const float* bfp = (const float*)d_in[3];
  const float* Wb  = (const float*)d_in[4];
  const float* Ub  = (const float*)d_in[5];
  const float* bbp = (const float*)d_in[6];
  const float* w1  = (const float*)d_in[7];
  const float* b1  = (const float*)d_in[8];
  const float* w2  = (const float*)d_in[9];
  const float* b2  = (const float*)d_in[10];
  const float* w3  = (const float*)d_in[11];
  const float* b3  = (const float*)d_in[12];

  unsigned short* hfbuf = (unsigned short*)d_ws;                 // 16M bf16 = 33.5 MB
  unsigned short* hbbuf = hfbuf + (size_t)NPIX * TT * FF;        // +33.5 MB
  float* Wc = (float*)(hbbuf + (size_t)NPIX * TT * FF);          // 320 floats
  float* bc = Wc + 320;                                          // 16 floats

  fold_kernel<<<1, 512, 0, stream>>>(w1, b1, w2, b2, w3, b3, Wc, bc);

  lstm_kernel<<<dim3(256, 2), 512, 0, stream>>>(x, Wf, Uf, bfp, Wb, Ub, bbp, hfbuf, hbbuf);

  const int npos = NPIX * TT;  // 1,048,576
  dense_kernel<<<npos / 256, 256, 0, stream>>>(hfbuf, hbbuf, Wc, bc, (float*)d_out);
}

// Round 3
// 299.233 us; speedup vs baseline: 2.1940x; 2.0728x over previous
//
#include <hip/hip_runtime.h>
#include <hip/hip_bf16.h>
#include <cstdint>
#include <cstddef>

#define TT 64
#define CC 32
#define FF 16
#define HWSZ 1024
#define NPIX 16384   // B*H*W = 16*32*32

typedef __attribute__((ext_vector_type(8))) short  short8;   // 8 bf16 (4 VGPRs)
typedef __attribute__((ext_vector_type(4))) float  f32x4;    // MFMA accumulator

__device__ __forceinline__ float bf2f(unsigned int u16) {
  union { unsigned int u; float f; } c;
  c.u = u16 << 16;
  return c.f;
}
__device__ __forceinline__ unsigned int f2bf(float f) {
  union { float f; unsigned int u; } c;
  c.f = f;
  unsigned int u = c.u;
  return (u + 0x7fffu + ((u >> 16) & 1u)) >> 16;  // RNE
}
__device__ __forceinline__ float clamp01(float x) {
  return fminf(fmaxf(x, 0.0f), 1.0f);
}
__device__ __forceinline__ float tanhf_fast(float x) {
  float e = __expf(2.0f * x);
  return 1.0f - 2.0f / (e + 1.0f);
}

// ---------------------------------------------------------------------------
// Fold the 3 linear layers: Wc = w1@w2@w3 [32x10], bc = b1@w2@w3 + b2@w3 + b3.
// ---------------------------------------------------------------------------
__global__ __launch_bounds__(512) void fold_kernel(
    const float* __restrict__ w1, const float* __restrict__ b1,
    const float* __restrict__ w2, const float* __restrict__ b2,
    const float* __restrict__ w3, const float* __restrict__ b3,
    float* __restrict__ Wc, float* __restrict__ bc)
{
  __shared__ float w23[16 * 10];
  __shared__ float bb2[16];
  const int t = threadIdx.x;

  if (t < 160) {
    const int k = t / 10, j = t % 10;
    float s = 0.0f;
    #pragma unroll
    for (int m = 0; m < 16; ++m) s = fmaf(w2[k * 16 + m], w3[m * 10 + j], s);
    w23[t] = s;
  }
  if (t < 16) {
    float s = b2[t];
    #pragma unroll
    for (int m = 0; m < 16; ++m) s = fmaf(b1[m], w2[m * 16 + t], s);
    bb2[t] = s;
  }
  __syncthreads();
  if (t < 320) {
    const int k = t / 10, j = t % 10;
    float s = 0.0f;
    #pragma unroll
    for (int m = 0; m < 16; ++m) s = fmaf(w1[k * 16 + m], w23[m * 10 + j], s);
    Wc[t] = s;
  }
  if (t < 10) {
    float s = b3[t];
    #pragma unroll
    for (int m = 0; m < 16; ++m) s = fmaf(bb2[m], w3[m * 10 + t], s);
    bc[t] = s;
  }
}

// ---------------------------------------------------------------------------
// MFMA LSTM. Wave = 16 pixels. v_mfma_f32_16x16x32_bf16:
//   A: lane(m = l&15, k = 8*(l>>4)+j)   B: lane(n = l&15, k = 8*(l>>4)+j)
//   C: lane(col = l&15, row = (l>>4)*4 + reg)
// N-tiles = gate types (i,f,g,o: cols 16nt..16nt+15). K-tile0: x@W (K=32=C).
// K-tile1: h@U (K=16 real + 16 zero-pad, zeros on BOTH A and B sides).
// Weights: 32 VGPRs of B-frags, loaded ONCE. c-state: 4 VGPRs/lane.
// No __syncthreads in the time loop (per-wave LDS h-staging only).
// ---------------------------------------------------------------------------
__global__ __launch_bounds__(256) void lstm_kernel(
    const float* __restrict__ x,
    const float* __restrict__ Wf, const float* __restrict__ Uf, const float* __restrict__ bfp,
    const float* __restrict__ Wb, const float* __restrict__ Ub, const float* __restrict__ bbp,
    unsigned short* __restrict__ hf_out, unsigned short* __restrict__ hb_out)
{
  const int dir = blockIdx.y;
  const float* __restrict__ Wp = dir ? Wb : Wf;
  const float* __restrict__ Up = dir ? Ub : Uf;
  const float* __restrict__ bp = dir ? bbp : bfp;
  unsigned short* __restrict__ hout = dir ? hb_out : hf_out;

  const int tid  = threadIdx.x;
  const int lane = tid & 63;
  const int wid  = tid >> 6;       // wave in block, 0..3
  const int quad = lane >> 4;      // 0..3
  const int l15  = lane & 15;

  // per-wave h staging: [16 px][40 shorts] (stride 80 B; shorts 16..31 = K-pad,
  // stay zero forever; 32..39 = bank-conflict pad). 16B-aligned rows (80=5*16).
  __shared__ unsigned short hst[4 * 16 * 40];
  unsigned short* hwv = hst + wid * 16 * 40;
  for (int i = tid; i < 4 * 16 * 40; i += 256) hst[i] = 0;
  __syncthreads();  // once, before the time loop

  const int px  = (blockIdx.x * 4 + wid) * 16 + l15;  // this lane's pixel (M role)
  const int b   = px >> 10;
  const int hwi = px & 1023;

  // ---- B fragments (weights), loaded once into VGPRs ----
  short8 Bx[4], Bu[4];
  #pragma unroll
  for (int nt = 0; nt < 4; ++nt) {
    short8 vx, vu;
    #pragma unroll
    for (int j = 0; j < 8; ++j) {
      const int k   = quad * 8 + j;
      const int col = nt * 16 + l15;
      vx[j] = (short)f2bf(Wp[k * 64 + col]);
      vu[j] = (k < FF) ? (short)f2bf(Up[k * 64 + col]) : (short)0;
    }
    Bx[nt] = vx; Bu[nt] = vu;
  }
  // per-lane biases (gate col = l15); fold hard_sigmoid: clamp(0.2z + (0.2b+0.5))
  const float bi = fmaf(bp[ 0 + l15], 0.2f, 0.5f);
  const float bf = fmaf(bp[16 + l15], 0.2f, 0.5f);
  const float bg = bp[32 + l15];
  const float bo = fmaf(bp[48 + l15], 0.2f, 0.5f);

  float cst[4] = {0.f, 0.f, 0.f, 0.f};  // c-state: rows px=(quad*4+r), col f=l15
  const int rd_off = l15 * 40 + quad * 8;  // A-frag read: h[m=l15][k=8*quad + j]
  int t_prev = 0;

  for (int s = 0; s < TT; ++s) {
    const int t = dir ? (TT - 1 - s) : s;
    const size_t pos = (size_t)(b * TT + t) * HWSZ + hwi;

    // x A-frag: 8 fp32 -> bf16x8
    const float* xp = x + pos * CC + quad * 8;
    const float4 x0 = *reinterpret_cast<const float4*>(xp);
    const float4 x1 = *reinterpret_cast<const float4*>(xp + 4);
    short8 ax;
    ax[0] = (short)f2bf(x0.x); ax[1] = (short)f2bf(x0.y);
    ax[2] = (short)f2bf(x0.z); ax[3] = (short)f2bf(x0.w);
    ax[4] = (short)f2bf(x1.x); ax[5] = (short)f2bf(x1.y);
    ax[6] = (short)f2bf(x1.z); ax[7] = (short)f2bf(x1.w);

    // previous step's h, in A-frag layout (zeros at s=0 / k>=16)
    const short8 ah = *reinterpret_cast<const short8*>(hwv + rd_off);

    // store previous h to global (lanes 0..31 hold the real K=0..15 halves)
    if (s > 0 && lane < 32) {
      const size_t pprev = (size_t)(b * TT + t_prev) * HWSZ + hwi;
      *reinterpret_cast<short8*>(hout + pprev * 16 + quad * 8) = ah;
    }

    f32x4 zi = {0.f, 0.f, 0.f, 0.f}, zf = zi, zg = zi, zo = zi;
    zi = __builtin_amdgcn_mfma_f32_16x16x32_bf16(ax, Bx[0], zi, 0, 0, 0);
    zf = __builtin_amdgcn_mfma_f32_16x16x32_bf16(ax, Bx[1], zf, 0, 0, 0);
    zg = __builtin_amdgcn_mfma_f32_16x16x32_bf16(ax, Bx[2], zg, 0, 0, 0);
    zo = __builtin_amdgcn_mfma_f32_16x16x32_bf16(ax, Bx[3], zo, 0, 0, 0);
    zi = __builtin_amdgcn_mfma_f32_16x16x32_bf16(ah, Bu[0], zi, 0, 0, 0);
    zf = __builtin_amdgcn_mfma_f32_16x16x32_bf16(ah, Bu[1], zf, 0, 0, 0);
    zg = __builtin_amdgcn_mfma_f32_16x16x32_bf16(ah, Bu[2], zg, 0, 0, 0);
    zo = __builtin_amdgcn_mfma_f32_16x16x32_bf16(ah, Bu[3], zo, 0, 0, 0);

    // epilogue: lane owns (px = quad*4+r, f = l15) for r=0..3
    #pragma unroll
    for (int r = 0; r < 4; ++r) {
      const float ig = clamp01(fmaf(zi[r], 0.2f, bi));
      const float fg = clamp01(fmaf(zf[r], 0.2f, bf));
      const float og = clamp01(fmaf(zo[r], 0.2f, bo));
      const float gg = tanhf_fast(zg[r] + bg);
      cst[r] = fmaf(fg, cst[r], ig * gg);
      const float hv = og * tanhf_fast(cst[r]);
      hwv[(quad * 4 + r) * 40 + l15] = (unsigned short)f2bf(hv);
    }
    t_prev = t;
  }

  // final h store
  const short8 ahf = *reinterpret_cast<const short8*>(hwv + rd_off);
  if (lane < 32) {
    const size_t pprev = (size_t)(b * TT + t_prev) * HWSZ + hwi;
    *reinterpret_cast<short8*>(hout + pprev * 16 + quad * 8) = ahf;
  }
}

// ---------------------------------------------------------------------------
// Dense (collapsed): Wc broadcast from LDS (no per-FMA global/K$ fetch).
// One thread per position: 32 bf16 in -> 10 fp32 out.
// ---------------------------------------------------------------------------
__global__ __launch_bounds__(256) void dense_kernel(
    const unsigned short* __restrict__ hf, const unsigned short* __restrict__ hb,
    const float* __restrict__ Wc, const float* __restrict__ bc,
    float* __restrict__ out)
{
  __shared__ float w[320];
  __shared__ float bb[10];
  for (int i = threadIdx.x; i < 320; i += 256) w[i] = Wc[i];
  if (threadIdx.x < 10) bb[threadIdx.x] = bc[threadIdx.x];
  __syncthreads();

  const size_t pos = (size_t)blockIdx.x * 256 + threadIdx.x;

  const uint4* hf4 = reinterpret_cast<const uint4*>(hf) + pos * 2;
  const uint4* hb4 = reinterpret_cast<const uint4*>(hb) + pos * 2;
  uint4 q0 = hf4[0], q1 = hf4[1], q2 = hb4[0], q3 = hb4[1];
  unsigned int uw[16] = {q0.x, q0.y, q0.z, q0.w, q1.x, q1.y, q1.z, q1.w,
                         q2.x, q2.y, q2.z, q2.w, q3.x, q3.y, q3.z, q3.w};
  float hin[32];
  #pragma unroll
  for (int i = 0; i < 16; ++i) {
    hin[2 * i]     = bf2f(uw[i] & 0xffffu);
    hin[2 * i + 1] = bf2f(uw[i] >> 16);
  }

  float acc[10];
  #pragma unroll
  for (int j = 0; j < 10; ++j) acc[j] = bb[j];
  #pragma unroll
  for (int k = 0; k < 32; ++k) {
    const float v = hin[k];
    #pragma unroll
    for (int j = 0; j < 10; ++j) acc[j] = fmaf(v, w[k * 10 + j], acc[j]);
  }

  float2* o2 = reinterpret_cast<float2*>(out + pos * 10);
  o2[0] = make_float2(acc[0], acc[1]);
  o2[1] = make_float2(acc[2], acc[3]);
  o2[2] = make_float2(acc[4], acc[5]);
  o2[3] = make_float2(acc[6], acc[7]);
  o2[4] = make_float2(acc[8], acc[9]);
}

extern "C" void kernel_launch(void* const* d_in, const int* in_sizes, int n_in,
                              void* d_out, int out_size, void* d_ws, size_t ws_size,
                              hipStream_t stream) {
  const float* x   = (const float*)d_in[0];
  const float* Wf  = (const float*)d_in[1];
  const float* Uf  = (const float*)d_in[2];
  const float* bfp = (const float*)d_in[3];
  const float* Wb  = (const float*)d_in[4];
  const float* Ub  = (const float*)d_in[5];
  const float* bbp = (const float*)d_in[6];
  const float* w1  = (const float*)d_in[7];
  const float* b1  = (const float*)d_in[8];
  const float* w2  = (const float*)d_in[9];
  const float* b2  = (const float*)d_in[10];
  const float* w3  = (const float*)d_in[11];
  const float* b3  = (const float*)d_in[12];

  unsigned short* hfbuf = (unsigned short*)d_ws;                 // 16M bf16 = 33.5 MB
  unsigned short* hbbuf = hfbuf + (size_t)NPIX * TT * FF;        // +33.5 MB
  float* Wc = (float*)(hbbuf + (size_t)NPIX * TT * FF);          // 320 floats
  float* bc = Wc + 320;                                          // 10 floats

  fold_kernel<<<1, 512, 0, stream>>>(w1, b1, w2, b2, w3, b3, Wc, bc);

  // 256 blocks x 4 waves x 16 px = 16384 px, x2 directions
  lstm_kernel<<<dim3(256, 2), 256, 0, stream>>>(x, Wf, Uf, bfp, Wb, Ub, bbp, hfbuf, hbbuf);

  const int npos = NPIX * TT;  // 1,048,576
  dense_kernel<<<npos / 256, 256, 0, stream>>>(hfbuf, hbbuf, Wc, bc, (float*)d_out);
}

// Round 4
// 282.930 us; speedup vs baseline: 2.3204x; 1.0576x over previous
//
#include <hip/hip_runtime.h>
#include <hip/hip_bf16.h>
#include <cstdint>
#include <cstddef>

#define TT 64
#define CC 32
#define FF 16
#define HWSZ 1024
#define NPIX 16384   // B*H*W = 16*32*32

typedef __attribute__((ext_vector_type(8))) short  short8;   // 8 bf16 (4 VGPRs)
typedef __attribute__((ext_vector_type(4))) float  f32x4;    // MFMA accumulator

__device__ __forceinline__ float bf2f(unsigned int u16) {
  union { unsigned int u; float f; } c;
  c.u = u16 << 16;
  return c.f;
}
__device__ __forceinline__ unsigned int f2bf(float f) {
  union { float f; unsigned int u; } c;
  c.f = f;
  unsigned int u = c.u;
  return (u + 0x7fffu + ((u >> 16) & 1u)) >> 16;  // RNE
}
// packed fp32x2 -> bf16x2 (v_cvt_pk path via hip_bf16)
__device__ __forceinline__ unsigned int pkbf(float a, float b) {
  float2 f2; f2.x = a; f2.y = b;
  __hip_bfloat162 h = __float22bfloat162_rn(f2);
  union { __hip_bfloat162 h; unsigned int u; } c; c.h = h;
  return c.u;
}
__device__ __forceinline__ float clamp01(float x) {
  return fminf(fmaxf(x, 0.0f), 1.0f);
}

#define L2E2 2.8853900817779268f   // 2*log2(e):  tanh(v) = 1 - 2/(exp2(v*L2E2)+1)
__device__ __forceinline__ float tanh_e2(float e2arg) {
  const float e = __builtin_exp2f(e2arg);
  const float t = __builtin_amdgcn_rcpf(e + 1.0f);
  return fmaf(-2.0f, t, 1.0f);
}

// ---------------------------------------------------------------------------
// Fold the 3 linear layers: Wc = w1@w2@w3 [32x10], bc = b1@w2@w3 + b2@w3 + b3.
// ---------------------------------------------------------------------------
__global__ __launch_bounds__(512) void fold_kernel(
    const float* __restrict__ w1, const float* __restrict__ b1,
    const float* __restrict__ w2, const float* __restrict__ b2,
    const float* __restrict__ w3, const float* __restrict__ b3,
    float* __restrict__ Wc, float* __restrict__ bc)
{
  __shared__ float w23[16 * 10];
  __shared__ float bb2[16];
  const int t = threadIdx.x;

  if (t < 160) {
    const int k = t / 10, j = t % 10;
    float s = 0.0f;
    #pragma unroll
    for (int m = 0; m < 16; ++m) s = fmaf(w2[k * 16 + m], w3[m * 10 + j], s);
    w23[t] = s;
  }
  if (t < 16) {
    float s = b2[t];
    #pragma unroll
    for (int m = 0; m < 16; ++m) s = fmaf(b1[m], w2[m * 16 + t], s);
    bb2[t] = s;
  }
  __syncthreads();
  if (t < 320) {
    const int k = t / 10, j = t % 10;
    float s = 0.0f;
    #pragma unroll
    for (int m = 0; m < 16; ++m) s = fmaf(w1[k * 16 + m], w23[m * 10 + j], s);
    Wc[t] = s;
  }
  if (t < 10) {
    float s = b3[t];
    #pragma unroll
    for (int m = 0; m < 16; ++m) s = fmaf(bb2[m], w3[m * 10 + t], s);
    bc[t] = s;
  }
}

// ---------------------------------------------------------------------------
// MFMA LSTM. Wave = 16 pixels. v_mfma_f32_16x16x32_bf16:
//   A: lane(m=l&15, k=8*(l>>4)+j)  B: lane(n=l&15, k=8*(l>>4)+j)
//   C: lane(col=l&15, row=(l>>4)*4+reg)
// Weights live in 32 VGPRs of B-frags (loaded once). 32-bit strength-reduced
// byte offsets; next-step x prefetch; packed bf16 converts; exp2/rcp tanh.
// ---------------------------------------------------------------------------
__global__ __launch_bounds__(256) void lstm_kernel(
    const float* __restrict__ x,
    const float* __restrict__ Wf, const float* __restrict__ Uf, const float* __restrict__ bfp,
    const float* __restrict__ Wb, const float* __restrict__ Ub, const float* __restrict__ bbp,
    unsigned short* __restrict__ hf_out, unsigned short* __restrict__ hb_out)
{
  const int dir = blockIdx.y;
  const float* __restrict__ Wp = dir ? Wb : Wf;
  const float* __restrict__ Up = dir ? Ub : Uf;
  const float* __restrict__ bp = dir ? bbp : bfp;
  unsigned short* __restrict__ hout = dir ? hb_out : hf_out;

  const int tid  = threadIdx.x;
  const int lane = tid & 63;
  const int wid  = tid >> 6;       // wave in block, 0..3
  const int quad = lane >> 4;      // 0..3
  const int l15  = lane & 15;

  // per-wave h staging: [16 px][40 shorts] (stride 80 B; 16..31 = K-pad zeros)
  __shared__ unsigned short hst[4 * 16 * 40];
  unsigned short* hwv = hst + wid * 16 * 40;
  for (int i = tid; i < 4 * 16 * 40; i += 256) hst[i] = 0;
  __syncthreads();  // once, before the time loop

  const int px  = (blockIdx.x * 4 + wid) * 16 + l15;
  const int b   = px >> 10;
  const int hwi = px & 1023;

  // ---- B fragments (weights), loaded once into VGPRs ----
  short8 Bx[4], Bu[4];
  #pragma unroll
  for (int nt = 0; nt < 4; ++nt) {
    short8 vx, vu;
    #pragma unroll
    for (int j = 0; j < 8; ++j) {
      const int k   = quad * 8 + j;
      const int col = nt * 16 + l15;
      vx[j] = (short)f2bf(Wp[k * 64 + col]);
      vu[j] = (k < FF) ? (short)f2bf(Up[k * 64 + col]) : (short)0;
    }
    Bx[nt] = vx; Bu[nt] = vu;
  }
  // per-lane biases (gate col = l15); hard_sigmoid folded: clamp(0.2z+(0.2b+0.5))
  const float bi  = fmaf(bp[ 0 + l15], 0.2f, 0.5f);
  const float bf  = fmaf(bp[16 + l15], 0.2f, 0.5f);
  const float bgl = bp[32 + l15] * L2E2;          // pre-scaled for exp2
  const float bo  = fmaf(bp[48 + l15], 0.2f, 0.5f);

  float cst[4] = {0.f, 0.f, 0.f, 0.f};
  const int rd_off = l15 * 40 + quad * 8;  // A-frag read: h[m=l15][k=8*quad+j]

  // strength-reduced byte offsets
  const int t0 = dir ? (TT - 1) : 0;
  const unsigned int pos0 = (unsigned int)((b * TT + t0) * HWSZ + hwi);
  unsigned int xoff = pos0 * (CC * 4) + quad * 32;
  const int xstep = dir ? -(HWSZ * CC * 4) : (HWSZ * CC * 4);
  unsigned int hob = pos0 * 32 + quad * 16;     // valid for lanes<32 (quad 0/1)
  const int hstep = dir ? -(HWSZ * 32) : (HWSZ * 32);
  unsigned int hob_prev = hob;

  const char* xb = (const char*)x;
  char* hbb = (char*)hout;

  float4 x0 = *reinterpret_cast<const float4*>(xb + xoff);
  float4 x1 = *reinterpret_cast<const float4*>(xb + xoff + 16);

  for (int s = 0; s < TT; ++s) {
    union { short8 s8; unsigned int u[4]; } ax;
    ax.u[0] = pkbf(x0.x, x0.y); ax.u[1] = pkbf(x0.z, x0.w);
    ax.u[2] = pkbf(x1.x, x1.y); ax.u[3] = pkbf(x1.z, x1.w);

    if (s + 1 < TT) {   // prefetch next step's x
      xoff += xstep;
      x0 = *reinterpret_cast<const float4*>(xb + xoff);
      x1 = *reinterpret_cast<const float4*>(xb + xoff + 16);
    }

    // previous step's h in A-frag layout (zeros at s=0 / k>=16)
    const short8 ah = *reinterpret_cast<const short8*>(hwv + rd_off);

    if (s > 0 && lane < 32) {   // deferred global store of h[t_prev]
      *reinterpret_cast<short8*>(hbb + hob_prev) = ah;
    }

    f32x4 zi = {0.f, 0.f, 0.f, 0.f}, zf = zi, zg = zi, zo = zi;
    zi = __builtin_amdgcn_mfma_f32_16x16x32_bf16(ax.s8, Bx[0], zi, 0, 0, 0);
    zf = __builtin_amdgcn_mfma_f32_16x16x32_bf16(ax.s8, Bx[1], zf, 0, 0, 0);
    zg = __builtin_amdgcn_mfma_f32_16x16x32_bf16(ax.s8, Bx[2], zg, 0, 0, 0);
    zo = __builtin_amdgcn_mfma_f32_16x16x32_bf16(ax.s8, Bx[3], zo, 0, 0, 0);
    zi = __builtin_amdgcn_mfma_f32_16x16x32_bf16(ah, Bu[0], zi, 0, 0, 0);
    zf = __builtin_amdgcn_mfma_f32_16x16x32_bf16(ah, Bu[1], zf, 0, 0, 0);
    zg = __builtin_amdgcn_mfma_f32_16x16x32_bf16(ah, Bu[2], zg, 0, 0, 0);
    zo = __builtin_amdgcn_mfma_f32_16x16x32_bf16(ah, Bu[3], zo, 0, 0, 0);

    // epilogue: lane owns (px = quad*4+r, f = l15)
    float hv[4];
    #pragma unroll
    for (int r = 0; r < 4; ++r) {
      const float ig = clamp01(fmaf(zi[r], 0.2f, bi));
      const float fg = clamp01(fmaf(zf[r], 0.2f, bf));
      const float og = clamp01(fmaf(zo[r], 0.2f, bo));
      const float gg = tanh_e2(fmaf(zg[r], L2E2, bgl));
      cst[r] = fmaf(fg, cst[r], ig * gg);
      hv[r]  = og * tanh_e2(cst[r] * L2E2);
    }
    const unsigned int p01 = pkbf(hv[0], hv[1]);
    const unsigned int p23 = pkbf(hv[2], hv[3]);
    const int wr = quad * 4 * 40 + l15;
    hwv[wr          ] = (unsigned short)(p01 & 0xffffu);
    hwv[wr + 40     ] = (unsigned short)(p01 >> 16);
    hwv[wr + 80     ] = (unsigned short)(p23 & 0xffffu);
    hwv[wr + 120    ] = (unsigned short)(p23 >> 16);

    hob_prev = hob;
    hob += hstep;
  }

  // final h store
  const short8 ahf = *reinterpret_cast<const short8*>(hwv + rd_off);
  if (lane < 32) {
    *reinterpret_cast<short8*>(hbb + hob_prev) = ahf;
  }
}

// ---------------------------------------------------------------------------
// Dense via MFMA: out[1M x 10] = [hf|hb] @ Wc + bc.  Wave = 16 positions/tile.
// A-frag straight from the h buffers (16B/lane). Wc as bf16 hi+lo B-frags
// (2 chained MFMAs => fp32-accurate weights). Bias in the C init.
// ---------------------------------------------------------------------------
__global__ __launch_bounds__(256) void dense_kernel(
    const unsigned short* __restrict__ hf, const unsigned short* __restrict__ hb,
    const float* __restrict__ Wc, const float* __restrict__ bc,
    float* __restrict__ out)
{
  const int tid  = threadIdx.x;
  const int lane = tid & 63;
  const int quad = lane >> 4;
  const int l15  = lane & 15;

  // B fragments: B[n=l15][k=8*quad+j], k<16 -> hf features, k>=16 -> hb
  short8 Bhi, Blo;
  #pragma unroll
  for (int j = 0; j < 8; ++j) {
    const int k = quad * 8 + j;
    const float v  = (l15 < 10) ? Wc[k * 10 + l15] : 0.0f;
    const unsigned int hi = f2bf(v);
    const float lo = v - bf2f(hi);
    Bhi[j] = (short)hi;
    Blo[j] = (short)f2bf(lo);
  }
  const float bcv = (l15 < 10) ? bc[l15] : 0.0f;

  const unsigned short* __restrict__ src = (quad & 2) ? hb : hf;
  const unsigned int lsub = (quad & 1) * 8;

  const unsigned int gw = (blockIdx.x * 256 + tid) >> 6;  // global wave 0..8191

  #pragma unroll
  for (int i = 0; i < 8; ++i) {
    const unsigned int tile  = gw * 8 + i;
    const unsigned int pos16 = tile * 16 + l15;
    const short8 A = *reinterpret_cast<const short8*>(src + pos16 * 16 + lsub);

    f32x4 acc = {bcv, bcv, bcv, bcv};
    acc = __builtin_amdgcn_mfma_f32_16x16x32_bf16(A, Bhi, acc, 0, 0, 0);
    acc = __builtin_amdgcn_mfma_f32_16x16x32_bf16(A, Blo, acc, 0, 0, 0);

    if (l15 < 10) {
      const unsigned int rowbase = tile * 16 + quad * 4;
      #pragma unroll
      for (int r = 0; r < 4; ++r) {
        out[(size_t)(rowbase + r) * 10 + l15] = acc[r];
      }
    }
  }
}

extern "C" void kernel_launch(void* const* d_in, const int* in_sizes, int n_in,
                              void* d_out, int out_size, void* d_ws, size_t ws_size,
                              hipStream_t stream) {
  const float* x   = (const float*)d_in[0];
  const float* Wf  = (const float*)d_in[1];
  const float* Uf  = (const float*)d_in[2];
  const float* bfp = (const float*)d_in[3];
  const float* Wb  = (const float*)d_in[4];
  const float* Ub  = (const float*)d_in[5];
  const float* bbp = (const float*)d_in[6];
  const float* w1  = (const float*)d_in[7];
  const float* b1  = (const float*)d_in[8];
  const float* w2  = (const float*)d_in[9];
  const float* b2  = (const float*)d_in[10];
  const float* w3  = (const float*)d_in[11];
  const float* b3  = (const float*)d_in[12];

  unsigned short* hfbuf = (unsigned short*)d_ws;                 // 16M bf16 = 33.5 MB
  unsigned short* hbbuf = hfbuf + (size_t)NPIX * TT * FF;        // +33.5 MB
  float* Wc = (float*)(hbbuf + (size_t)NPIX * TT * FF);          // 320 floats
  float* bc = Wc + 320;                                          // 10 floats

  fold_kernel<<<1, 512, 0, stream>>>(w1, b1, w2, b2, w3, b3, Wc, bc);

  // 256 blocks x 4 waves x 16 px = 16384 px, x2 directions
  lstm_kernel<<<dim3(256, 2), 256, 0, stream>>>(x, Wf, Uf, bfp, Wb, Ub, bbp, hfbuf, hbbuf);

  // 1M positions / 16-per-wave / 8-tiles-per-wave = 8192 waves = 2048 blocks
  dense_kernel<<<2048, 256, 0, stream>>>(hfbuf, hbbuf, Wc, bc, (float*)d_out);
}

// Round 5
// 277.730 us; speedup vs baseline: 2.3638x; 1.0187x over previous
//
#include <hip/hip_runtime.h>
#include <hip/hip_bf16.h>
#include <cstdint>
#include <cstddef>

#define TT 64
#define CC 32
#define FF 16
#define HWSZ 1024
#define NPIX 16384   // B*H*W = 16*32*32

typedef __attribute__((ext_vector_type(8))) short  short8;   // 8 bf16 (4 VGPRs)
typedef __attribute__((ext_vector_type(4))) float  f32x4;    // MFMA accumulator

__device__ __forceinline__ float bf2f(unsigned int u16) {
  union { unsigned int u; float f; } c;
  c.u = u16 << 16;
  return c.f;
}
__device__ __forceinline__ unsigned int f2bf(float f) {
  union { float f; unsigned int u; } c;
  c.f = f;
  unsigned int u = c.u;
  return (u + 0x7fffu + ((u >> 16) & 1u)) >> 16;  // RNE
}
// packed fp32x2 -> bf16x2
__device__ __forceinline__ unsigned int pkbf(float a, float b) {
  float2 f2; f2.x = a; f2.y = b;
  __hip_bfloat162 h = __float22bfloat162_rn(f2);
  union { __hip_bfloat162 h; unsigned int u; } c; c.h = h;
  return c.u;
}
__device__ __forceinline__ float clamp01(float x) {
  return fminf(fmaxf(x, 0.0f), 1.0f);
}

#define L2E2 2.8853900817779268f   // 2*log2(e):  tanh(v) = 1 - 2/(exp2(v*L2E2)+1)
__device__ __forceinline__ float tanh_e2(float e2arg) {
  const float e = __builtin_exp2f(e2arg);
  const float t = __builtin_amdgcn_rcpf(e + 1.0f);
  return fmaf(-2.0f, t, 1.0f);
}

// ---------------------------------------------------------------------------
// Fold the 3 linear layers: Wc = w1@w2@w3 [32x10], bc = b1@w2@w3 + b2@w3 + b3.
// ---------------------------------------------------------------------------
__global__ __launch_bounds__(512) void fold_kernel(
    const float* __restrict__ w1, const float* __restrict__ b1,
    const float* __restrict__ w2, const float* __restrict__ b2,
    const float* __restrict__ w3, const float* __restrict__ b3,
    float* __restrict__ Wc, float* __restrict__ bc)
{
  __shared__ float w23[16 * 10];
  __shared__ float bb2[16];
  const int t = threadIdx.x;

  if (t < 160) {
    const int k = t / 10, j = t % 10;
    float s = 0.0f;
    #pragma unroll
    for (int m = 0; m < 16; ++m) s = fmaf(w2[k * 16 + m], w3[m * 10 + j], s);
    w23[t] = s;
  }
  if (t < 16) {
    float s = b2[t];
    #pragma unroll
    for (int m = 0; m < 16; ++m) s = fmaf(b1[m], w2[m * 16 + t], s);
    bb2[t] = s;
  }
  __syncthreads();
  if (t < 320) {
    const int k = t / 10, j = t % 10;
    float s = 0.0f;
    #pragma unroll
    for (int m = 0; m < 16; ++m) s = fmaf(w1[k * 16 + m], w23[m * 10 + j], s);
    Wc[t] = s;
  }
  if (t < 10) {
    float s = b3[t];
    #pragma unroll
    for (int m = 0; m < 16; ++m) s = fmaf(bb2[m], w3[m * 10 + t], s);
    bc[t] = s;
  }
}

// ---------------------------------------------------------------------------
// Transposed-MFMA LSTM, zero LDS, bpermute h-exchange.
//   z^T[f][px] : A = weights^T (m=f, k=c), B = x/h (n=px, k=c)
//   A/B frag: lane(idx = l&15, k = 8*(l>>4)+j).  C: lane(n=l&15, m=(l>>4)*4+r)
// Per step on the critical path: 4 MFMA (h@U chained on precomputed zx) ->
// epilogue -> pack -> 4 ds_bpermute -> next step. x@W for step s+1 is
// computed off-path; x loads prefetched 2 iterations deep.
// ---------------------------------------------------------------------------
__global__ __launch_bounds__(256) void lstm_kernel(
    const float* __restrict__ x,
    const float* __restrict__ Wf, const float* __restrict__ Uf, const float* __restrict__ bfp,
    const float* __restrict__ Wb, const float* __restrict__ Ub, const float* __restrict__ bbp,
    unsigned short* __restrict__ hf_out, unsigned short* __restrict__ hb_out)
{
  const int dir = blockIdx.y;
  const float* __restrict__ Wp = dir ? Wb : Wf;
  const float* __restrict__ Up = dir ? Ub : Uf;
  const float* __restrict__ bp = dir ? bbp : bfp;
  unsigned short* __restrict__ hout = dir ? hb_out : hf_out;

  const int tid  = threadIdx.x;
  const int lane = tid & 63;
  const int wid  = tid >> 6;       // wave in block, 0..3 (waves independent)
  const int quad = lane >> 4;      // 0..3
  const int l15  = lane & 15;

  const int px  = (blockIdx.x * 4 + wid) * 16 + l15;   // this lane's pixel (N role)
  const int b   = px >> 10;
  const int hwi = px & 1023;

  // ---- A fragments (weights^T), loaded once ----
  // AW[nt]: lane(q,p): W[k=8q+j][nt*16+p]     (k = input channel, m = filter p)
  // AU[nt]: lane(q,p): U[k=8q+j][nt*16+p] for k<16, else 0 (K-pad)
  short8 AW[4], AU[4];
  #pragma unroll
  for (int nt = 0; nt < 4; ++nt) {
    short8 vw, vu;
    #pragma unroll
    for (int j = 0; j < 8; ++j) {
      const int k   = quad * 8 + j;
      const int col = nt * 16 + l15;
      vw[j] = (short)f2bf(Wp[k * 64 + col]);
      vu[j] = (k < FF) ? (short)f2bf(Up[k * 64 + col]) : (short)0;
    }
    AW[nt] = vw; AU[nt] = vu;
  }

  // biases: lane(q,p) owns f = q*4+r (rows of C)
  float bi[4], bfv[4], bgl[4], bo[4];
  #pragma unroll
  for (int r = 0; r < 4; ++r) {
    const int f = quad * 4 + r;
    bi[r]  = fmaf(bp[ 0 + f], 0.2f, 0.5f);
    bfv[r] = fmaf(bp[16 + f], 0.2f, 0.5f);
    bgl[r] = bp[32 + f] * L2E2;
    bo[r]  = fmaf(bp[48 + f], 0.2f, 0.5f);
  }

  float cst[4] = {0.f, 0.f, 0.f, 0.f};
  union BU { short8 s8; int i[4]; };
  BU Bh; Bh.i[0] = 0; Bh.i[1] = 0; Bh.i[2] = 0; Bh.i[3] = 0;   // h = 0 at s=0

  // bpermute source byte-addresses (fixed per lane): src lane = 32q + 16*sel + p
  const int bp0 = (quad * 32 + l15) * 4;        // sel=0 (dwords 0,1)
  const int bp1 = (quad * 32 + 16 + l15) * 4;   // sel=1 (dwords 2,3)
  const bool kreal = (quad < 2);                // quads 2,3 are K-pad -> zeros

  // strength-reduced byte offsets
  const int t0 = dir ? (TT - 1) : 0;
  const unsigned int pos0 = (unsigned int)((b * TT + t0) * HWSZ + hwi);
  const int xstep = dir ? -(HWSZ * CC * 4) : (HWSZ * CC * 4);
  const int hstep = dir ? -(HWSZ * 32) : (HWSZ * 32);
  unsigned int hob = pos0 * 32 + quad * 16;     // h store (lanes<32)

  const char* xb = (const char*)x;
  char* hbb = (char*)hout;

  // ---- prologue: load x[0], x[1]; compute zx(x[0]); reload bufA <- x[2] ----
  const unsigned int xo0 = pos0 * (CC * 4) + quad * 32;
  float4 a0 = *reinterpret_cast<const float4*>(xb + xo0);
  float4 a1 = *reinterpret_cast<const float4*>(xb + xo0 + 16);
  const unsigned int xo1 = xo0 + xstep;
  float4 c0 = *reinterpret_cast<const float4*>(xb + xo1);
  float4 c1 = *reinterpret_cast<const float4*>(xb + xo1 + 16);
  unsigned int xoffL = xo1 + xstep;             // address of x[2]

  f32x4 zx[4];
  {
    BU ax;
    ax.i[0] = pkbf(a0.x, a0.y); ax.i[1] = pkbf(a0.z, a0.w);
    ax.i[2] = pkbf(a1.x, a1.y); ax.i[3] = pkbf(a1.z, a1.w);
    const f32x4 zz = {0.f, 0.f, 0.f, 0.f};
    #pragma unroll
    for (int nt = 0; nt < 4; ++nt)
      zx[nt] = __builtin_amdgcn_mfma_f32_16x16x32_bf16(AW[nt], ax.s8, zz, 0, 0, 0);
  }
  a0 = *reinterpret_cast<const float4*>(xb + xoffL);      // bufA <- x[2]
  a1 = *reinterpret_cast<const float4*>(xb + xoffL + 16);

  #pragma unroll 2
  for (int s = 0; s < TT; ++s) {
    // ---- on-path: z = zx + h @ U (single MFMA depth) ----
    f32x4 z[4];
    #pragma unroll
    for (int nt = 0; nt < 4; ++nt)
      z[nt] = __builtin_amdgcn_mfma_f32_16x16x32_bf16(AU[nt], Bh.s8, zx[nt], 0, 0, 0);

    // ---- off-path: zx for step s+1 from the buffer holding x[s+1] ----
    {
      const float4 u0 = (s & 1) ? a0 : c0;
      const float4 u1 = (s & 1) ? a1 : c1;
      BU ax;
      ax.i[0] = pkbf(u0.x, u0.y); ax.i[1] = pkbf(u0.z, u0.w);
      ax.i[2] = pkbf(u1.x, u1.y); ax.i[3] = pkbf(u1.z, u1.w);
      const f32x4 zz = {0.f, 0.f, 0.f, 0.f};
      #pragma unroll
      for (int nt = 0; nt < 4; ++nt)
        zx[nt] = __builtin_amdgcn_mfma_f32_16x16x32_bf16(AW[nt], ax.s8, zz, 0, 0, 0);
    }
    // ---- issue prefetch of x[s+3] into the buffer just consumed ----
    if (s + 3 < TT) xoffL += xstep;              // else re-load last (harmless)
    if (s & 1) {
      a0 = *reinterpret_cast<const float4*>(xb + xoffL);
      a1 = *reinterpret_cast<const float4*>(xb + xoffL + 16);
    } else {
      c0 = *reinterpret_cast<const float4*>(xb + xoffL);
      c1 = *reinterpret_cast<const float4*>(xb + xoffL + 16);
    }

    // ---- epilogue: lane(q,p) owns (f = q*4+r, px = p) ----
    float hv[4];
    #pragma unroll
    for (int r = 0; r < 4; ++r) {
      const float ig = clamp01(fmaf(z[0][r], 0.2f, bi[r]));
      const float fg = clamp01(fmaf(z[1][r], 0.2f, bfv[r]));
      const float og = clamp01(fmaf(z[3][r], 0.2f, bo[r]));
      const float gg = tanh_e2(fmaf(z[2][r], L2E2, bgl[r]));
      cst[r] = fmaf(fg, cst[r], ig * gg);
      hv[r]  = og * tanh_e2(cst[r] * L2E2);
    }

    // pack h pairs (f-major) and redistribute C-layout -> B-frag via bpermute
    const int p01 = (int)pkbf(hv[0], hv[1]);   // f = 4q, 4q+1  for pixel p
    const int p23 = (int)pkbf(hv[2], hv[3]);   // f = 4q+2, 4q+3
    int d0 = __builtin_amdgcn_ds_bpermute(bp0, p01);  // k = 8q'+0,1
    int d1 = __builtin_amdgcn_ds_bpermute(bp0, p23);  // k = 8q'+2,3
    int d2 = __builtin_amdgcn_ds_bpermute(bp1, p01);  // k = 8q'+4,5
    int d3 = __builtin_amdgcn_ds_bpermute(bp1, p23);  // k = 8q'+6,7
    Bh.i[0] = kreal ? d0 : 0;
    Bh.i[1] = kreal ? d1 : 0;
    Bh.i[2] = kreal ? d2 : 0;
    Bh.i[3] = kreal ? d3 : 0;

    // store h[t]: lanes q<2 hold h[8q..8q+7][p] = hout row halves (coalesced)
    if (lane < 32) {
      *reinterpret_cast<short8*>(hbb + hob) = Bh.s8;
    }
    hob += hstep;
  }
}

// ---------------------------------------------------------------------------
// Dense via MFMA: out[1M x 10] = [hf|hb] @ Wc + bc.  Wave = 16 positions/tile.
// A-frag straight from the h buffers (16B/lane). Wc as bf16 hi+lo B-frags
// (2 chained MFMAs => fp32-accurate weights). Bias in the C init.
// ---------------------------------------------------------------------------
__global__ __launch_bounds__(256) void dense_kernel(
    const unsigned short* __restrict__ hf, const unsigned short* __restrict__ hb,
    const float* __restrict__ Wc, const float* __restrict__ bc,
    float* __restrict__ out)
{
  const int tid  = threadIdx.x;
  const int lane = tid & 63;
  const int quad = lane >> 4;
  const int l15  = lane & 15;

  // B fragments: B[n=l15][k=8*quad+j], k<16 -> hf features, k>=16 -> hb
  short8 Bhi, Blo;
  #pragma unroll
  for (int j = 0; j < 8; ++j) {
    const int k = quad * 8 + j;
    const float v  = (l15 < 10) ? Wc[k * 10 + l15] : 0.0f;
    const unsigned int hi = f2bf(v);
    const float lo = v - bf2f(hi);
    Bhi[j] = (short)hi;
    Blo[j] = (short)f2bf(lo);
  }
  const float bcv = (l15 < 10) ? bc[l15] : 0.0f;

  const unsigned short* __restrict__ src = (quad & 2) ? hb : hf;
  const unsigned int lsub = (quad & 1) * 8;

  const unsigned int gw = (blockIdx.x * 256 + tid) >> 6;  // global wave 0..8191

  #pragma unroll
  for (int i = 0; i < 8; ++i) {
    const unsigned int tile  = gw * 8 + i;
    const unsigned int pos16 = tile * 16 + l15;
    const short8 A = *reinterpret_cast<const short8*>(src + pos16 * 16 + lsub);

    f32x4 acc = {bcv, bcv, bcv, bcv};
    acc = __builtin_amdgcn_mfma_f32_16x16x32_bf16(A, Bhi, acc, 0, 0, 0);
    acc = __builtin_amdgcn_mfma_f32_16x16x32_bf16(A, Blo, acc, 0, 0, 0);

    if (l15 < 10) {
      const unsigned int rowbase = tile * 16 + quad * 4;
      #pragma unroll
      for (int r = 0; r < 4; ++r) {
        out[(size_t)(rowbase + r) * 10 + l15] = acc[r];
      }
    }
  }
}

extern "C" void kernel_launch(void* const* d_in, const int* in_sizes, int n_in,
                              void* d_out, int out_size, void* d_ws, size_t ws_size,
                              hipStream_t stream) {
  const float* x   = (const float*)d_in[0];
  const float* Wf  = (const float*)d_in[1];
  const float* Uf  = (const float*)d_in[2];
  const float* bfp = (const float*)d_in[3];
  const float* Wb  = (const float*)d_in[4];
  const float* Ub  = (const float*)d_in[5];
  const float* bbp = (const float*)d_in[6];
  const float* w1  = (const float*)d_in[7];
  const float* b1  = (const float*)d_in[8];
  const float* w2  = (const float*)d_in[9];
  const float* b2  = (const float*)d_in[10];
  const float* w3  = (const float*)d_in[11];
  const float* b3  = (const float*)d_in[12];

  unsigned short* hfbuf = (unsigned short*)d_ws;                 // 16M bf16 = 33.5 MB
  unsigned short* hbbuf = hfbuf + (size_t)NPIX * TT * FF;        // +33.5 MB
  float* Wc = (float*)(hbbuf + (size_t)NPIX * TT * FF);          // 320 floats
  float* bc = Wc + 320;                                          // 10 floats

  fold_kernel<<<1, 512, 0, stream>>>(w1, b1, w2, b2, w3, b3, Wc, bc);

  // 256 blocks x 4 waves x 16 px = 16384 px, x2 directions
  lstm_kernel<<<dim3(256, 2), 256, 0, stream>>>(x, Wf, Uf, bfp, Wb, Ub, bbp, hfbuf, hbbuf);

  // 1M positions / 16-per-wave / 8-tiles-per-wave = 8192 waves = 2048 blocks
  dense_kernel<<<2048, 256, 0, stream>>>(hfbuf, hbbuf, Wc, bc, (float*)d_out);
}